// Round 1
// baseline (128.178 us; speedup 1.0000x reference)
//
#include <hip/hip_runtime.h>
#include <math.h>

#define N_ROWS 131072
#define U2_OFF 4096   // floats: Sw = ws[0..4095] (16x256), U2 = ws[4096..4351] (16x16)

// ---------------- stage-1 builder: 8-qubit state, 4 amps/lane ----------------
// amplitude index idx = 4*lane + k ; bit bp>=2 lives in lane bit (bp-2)

__device__ __forceinline__ void ry8(float v[4], int lane, int bp, float c, float s) {
  if (bp == 0) {            // pairs (0,1),(2,3)
    float n0 = fmaf(s, v[1], c * v[0]);
    float n1 = fmaf(-s, v[0], c * v[1]);
    float n2 = fmaf(s, v[3], c * v[2]);
    float n3 = fmaf(-s, v[2], c * v[3]);
    v[0] = n0; v[1] = n1; v[2] = n2; v[3] = n3;
  } else if (bp == 1) {     // pairs (0,2),(1,3)
    float n0 = fmaf(s, v[2], c * v[0]);
    float n2 = fmaf(-s, v[0], c * v[2]);
    float n1 = fmaf(s, v[3], c * v[1]);
    float n3 = fmaf(-s, v[1], c * v[3]);
    v[0] = n0; v[1] = n1; v[2] = n2; v[3] = n3;
  } else {
    int lm = 1 << (bp - 2);
    float sgn = ((lane >> (bp - 2)) & 1) ? -s : s;
#pragma unroll
    for (int k = 0; k < 4; ++k) {
      float o = __shfl_xor(v[k], lm);
      v[k] = fmaf(sgn, o, c * v[k]);
    }
  }
}

__device__ __forceinline__ void cnot8(float v[4], int lane, int cb, int tb) {
  if (cb >= 2 && tb >= 2) {
    int lm = 1 << (tb - 2);
    bool hc = (lane >> (cb - 2)) & 1;
#pragma unroll
    for (int k = 0; k < 4; ++k) {
      float o = __shfl_xor(v[k], lm);
      v[k] = hc ? o : v[k];
    }
  } else if (cb >= 2) {  // target in-register
    bool hc = (lane >> (cb - 2)) & 1;
    if (tb == 0) {
      float n0 = hc ? v[1] : v[0], n1 = hc ? v[0] : v[1];
      float n2 = hc ? v[3] : v[2], n3 = hc ? v[2] : v[3];
      v[0] = n0; v[1] = n1; v[2] = n2; v[3] = n3;
    } else {
      float n0 = hc ? v[2] : v[0], n2 = hc ? v[0] : v[2];
      float n1 = hc ? v[3] : v[1], n3 = hc ? v[1] : v[3];
      v[0] = n0; v[1] = n1; v[2] = n2; v[3] = n3;
    }
  } else if (tb >= 2) {  // control in-register, target cross-lane
    int lm = 1 << (tb - 2);
#pragma unroll
    for (int k = 0; k < 4; ++k) {
      float o = __shfl_xor(v[k], lm);
      if ((k >> cb) & 1) v[k] = o;
    }
  } else {               // both in-register
    if (cb == 0) { float t = v[1]; v[1] = v[3]; v[3] = t; }   // (cb,tb)=(0,1)
    else         { float t = v[2]; v[2] = v[3]; v[3] = t; }   // (cb,tb)=(1,0)
  }
}

// ---------------- stage-2 builder: full 16-dim state in registers ----------------
template <int BP>
__device__ __forceinline__ void ry16t(float* w, float c, float s) {
#pragma unroll
  for (int i = 0; i < 16; ++i) {
    if (((i >> BP) & 1) == 0) {
      const int j = i | (1 << BP);
      float a = w[i], b = w[j];
      w[i] = fmaf(s, b, c * a);
      w[j] = fmaf(-s, a, c * b);
    }
  }
}
__device__ __forceinline__ void ry16(float* w, int bp, float c, float s) {
  switch (bp) {
    case 0: ry16t<0>(w, c, s); break;
    case 1: ry16t<1>(w, c, s); break;
    case 2: ry16t<2>(w, c, s); break;
    default: ry16t<3>(w, c, s); break;
  }
}
template <int CB, int TB>
__device__ __forceinline__ void cnot16t(float* w) {
#pragma unroll
  for (int i = 0; i < 16; ++i) {
    if (((i >> CB) & 1) == 1 && ((i >> TB) & 1) == 0) {
      const int j = i | (1 << TB);
      float t = w[i]; w[i] = w[j]; w[j] = t;
    }
  }
}
__device__ __forceinline__ void cnot16(float* w, int cb, int tb) {
#define CC(a, b) if (cb == a && tb == b) { cnot16t<a, b>(w); return; }
  CC(0,1) CC(0,2) CC(0,3) CC(1,0) CC(1,2) CC(1,3)
  CC(2,0) CC(2,1) CC(2,3) CC(3,0) CC(3,1) CC(3,2)
#undef CC
}

__global__ void build_states_kernel(const float* __restrict__ thc,
                                    const float* __restrict__ th2,
                                    float* __restrict__ ws) {
  const int blk = blockIdx.x;
  const int lane = threadIdx.x;  // 64 threads
  if (blk < 16) {
    const float* th = thc + blk * 72;
    float v[4] = {0.f, 0.f, 0.f, 0.f};
    if (lane == 0) v[0] = 1.f;
    int p = 0;
    for (int m = 0; m < 8; ++m) {
#pragma unroll
      for (int q = 0; q < 8; ++q) {
        float a = 0.5f * th[p + q];
        ry8(v, lane, 7 - q, cosf(a), sinf(a));
      }
      p += 8;
#pragma unroll
      for (int q = 0; q < 8; ++q) {
        int tgt = (m % 2 == 0) ? ((q + 1) & 7) : ((q + 7) & 7);
        cnot8(v, lane, 7 - q, 7 - tgt);
      }
    }
#pragma unroll
    for (int q = 0; q < 8; ++q) {
      float a = 0.5f * th[p + q];
      ry8(v, lane, 7 - q, cosf(a), sinf(a));
    }
    float4* swv = (float4*)ws;
    swv[blk * 64 + lane] = make_float4(v[0], v[1], v[2], v[3]);
  } else {
    // U2[i][j] = ansatz(e_i)[j]; lane i (<16) builds row i entirely in registers
    float w[16];
#pragma unroll
    for (int j = 0; j < 16; ++j) w[j] = (j == lane) ? 1.f : 0.f;
    int p = 0;
    for (int m = 0; m < 8; ++m) {
#pragma unroll
      for (int q = 0; q < 4; ++q) {
        float a = 0.5f * th2[p + q];
        ry16(w, 3 - q, cosf(a), sinf(a));
      }
      p += 4;
#pragma unroll
      for (int q = 0; q < 4; ++q) {
        int tgt = (m % 2 == 0) ? ((q + 1) & 3) : ((q + 3) & 3);
        cnot16(w, 3 - q, 3 - tgt);
      }
    }
#pragma unroll
    for (int q = 0; q < 4; ++q) {
      float a = 0.5f * th2[p + q];
      ry16(w, 3 - q, cosf(a), sinf(a));
    }
    if (lane < 16) {
      float* u2 = ws + U2_OFF;
#pragma unroll
      for (int j = 0; j < 16; ++j) u2[lane * 16 + j] = w[j];
    }
  }
}

// ---------------- main kernel: one wave per row (grid-stride) ----------------
// lane = 16*g + c : g = x-segment (64 elems), c = channel
__global__ __launch_bounds__(256) void hadamard_main_kernel(
    const float* __restrict__ x, const float* __restrict__ ws,
    float* __restrict__ out) {
  const int lane = threadIdx.x & 63;
  const int wid = blockIdx.x * (blockDim.x >> 6) + (threadIdx.x >> 6);
  const int nw = gridDim.x * (blockDim.x >> 6);
  const int g = lane >> 4;
  const int c = lane & 15;

  // Sw chunk for (channel c, segment g): 64 floats in registers
  const float4* swv = (const float4*)ws;
  float4 sw[16];
#pragma unroll
  for (int i = 0; i < 16; ++i) sw[i] = swv[c * 64 + g * 16 + i];
  const float* u2 = ws + U2_OFF;
  const float4 u2q = *(const float4*)(u2 + c * 16 + g * 4);

  const float4* xv = (const float4*)x;
  for (int row = wid; row < N_ROWS; row += nw) {
    const float4* xr = xv + (size_t)row * 64 + g * 16;
    float z = 0.f;
#pragma unroll
    for (int i = 0; i < 16; ++i) {
      float4 t = xr[i];
      z = fmaf(t.x, sw[i].x, z);
      z = fmaf(t.y, sw[i].y, z);
      z = fmaf(t.z, sw[i].z, z);
      z = fmaf(t.w, sw[i].w, z);
    }
    // reduce over segments g (lane bits 4,5) -> full Z[c] on every lane
    z += __shfl_xor(z, 16);
    z += __shfl_xor(z, 32);

    // silu + nan_to_num
    float f = z / (1.f + __expf(-z));
    if (!isfinite(f)) f = 0.f;

    // normalize over 16 channels (lane bits 0..3)
    float ss = f * f;
    ss += __shfl_xor(ss, 1);
    ss += __shfl_xor(ss, 2);
    ss += __shfl_xor(ss, 4);
    ss += __shfl_xor(ss, 8);
    float fn = f / fmaxf(sqrtf(ss), 1e-6f);

    // S4[4g+jj] = sum_c fn_c * U2[c][4g+jj]
    float p0 = fn * u2q.x, p1 = fn * u2q.y, p2 = fn * u2q.z, p3 = fn * u2q.w;
    p0 += __shfl_xor(p0, 1); p1 += __shfl_xor(p1, 1); p2 += __shfl_xor(p2, 1); p3 += __shfl_xor(p3, 1);
    p0 += __shfl_xor(p0, 2); p1 += __shfl_xor(p1, 2); p2 += __shfl_xor(p2, 2); p3 += __shfl_xor(p3, 2);
    p0 += __shfl_xor(p0, 4); p1 += __shfl_xor(p1, 4); p2 += __shfl_xor(p2, 4); p3 += __shfl_xor(p3, 4);
    p0 += __shfl_xor(p0, 8); p1 += __shfl_xor(p1, 8); p2 += __shfl_xor(p2, 8); p3 += __shfl_xor(p3, 8);

    // normalize S4 over all 16 amplitudes (sum local 4, fold g)
    float s4 = p0 * p0 + p1 * p1 + p2 * p2 + p3 * p3;
    s4 += __shfl_xor(s4, 16);
    s4 += __shfl_xor(s4, 32);
    float inv = 1.f / fmaxf(sqrtf(s4), 1e-6f);
    float q0 = p0 * inv, q1 = p1 * inv, q2 = p2 * inv, q3 = p3 * inv;

    // marginalize first qubit: P[t] = q[t]^2 + q[t+8]^2  (partner = lane^32)
    float e0 = q0 * q0, e1 = q1 * q1, e2 = q2 * q2, e3 = q3 * q3;
    e0 += __shfl_xor(e0, 32);
    e1 += __shfl_xor(e1, 32);
    e2 += __shfl_xor(e2, 32);
    e3 += __shfl_xor(e3, 32);
    e0 = fmaxf(e0, 0.f); e1 = fmaxf(e1, 0.f); e2 = fmaxf(e2, 0.f); e3 = fmaxf(e3, 0.f);

    float psum = e0 + e1 + e2 + e3;
    psum += __shfl_xor(psum, 16);
    float rinv = 1.f / fmaxf(psum, 1e-6f);
    float P0 = e0 * rinv, P1 = e1 * rinv, P2 = e2 * rinv, P3 = e3 * rinv;
    float l0 = __logf(fmaxf(P0, 1e-12f));
    float l1 = __logf(fmaxf(P1, 1e-12f));
    float l2 = __logf(fmaxf(P2, 1e-12f));
    float l3 = __logf(fmaxf(P3, 1e-12f));

    if (c == 0 && g < 2) {  // lanes 0 and 16 write quads (g=0 -> P[0..3], g=1 -> P[4..7])
      *(float4*)(out + (size_t)row * 8 + g * 4) = make_float4(l0, l1, l2, l3);
      *(float4*)(out + (size_t)N_ROWS * 8 + (size_t)row * 8 + g * 4) =
          make_float4(P0, P1, P2, P3);
    }
  }
}

extern "C" void kernel_launch(void* const* d_in, const int* in_sizes, int n_in,
                              void* d_out, int out_size, void* d_ws, size_t ws_size,
                              hipStream_t stream) {
  const float* x = (const float*)d_in[0];
  const float* thc = (const float*)d_in[1];
  const float* th2 = (const float*)d_in[2];
  float* out = (float*)d_out;
  float* ws = (float*)d_ws;

  build_states_kernel<<<17, 64, 0, stream>>>(thc, th2, ws);
  hadamard_main_kernel<<<2048, 256, 0, stream>>>(x, ws, out);
}

// Round 2
// 113.322 us; speedup vs baseline: 1.1311x; 1.1311x over previous
//
#include <hip/hip_runtime.h>
#include <math.h>

#define N_ROWS 131072
#define U2_OFF 4096   // floats: Sw = ws[0..4095] (16x256), U2 = ws[4096..4351] (16x16)

// ---------------- stage-1 builder: 8-qubit state, 4 amps/lane ----------------
// amplitude index idx = 4*lane + k ; bit bp>=2 lives in lane bit (bp-2)

__device__ __forceinline__ void ry8(float v[4], int lane, int bp, float c, float s) {
  if (bp == 0) {            // pairs (0,1),(2,3)
    float n0 = fmaf(s, v[1], c * v[0]);
    float n1 = fmaf(-s, v[0], c * v[1]);
    float n2 = fmaf(s, v[3], c * v[2]);
    float n3 = fmaf(-s, v[2], c * v[3]);
    v[0] = n0; v[1] = n1; v[2] = n2; v[3] = n3;
  } else if (bp == 1) {     // pairs (0,2),(1,3)
    float n0 = fmaf(s, v[2], c * v[0]);
    float n2 = fmaf(-s, v[0], c * v[2]);
    float n1 = fmaf(s, v[3], c * v[1]);
    float n3 = fmaf(-s, v[1], c * v[3]);
    v[0] = n0; v[1] = n1; v[2] = n2; v[3] = n3;
  } else {
    int lm = 1 << (bp - 2);
    float sgn = ((lane >> (bp - 2)) & 1) ? -s : s;
#pragma unroll
    for (int k = 0; k < 4; ++k) {
      float o = __shfl_xor(v[k], lm);
      v[k] = fmaf(sgn, o, c * v[k]);
    }
  }
}

__device__ __forceinline__ void cnot8(float v[4], int lane, int cb, int tb) {
  if (cb >= 2 && tb >= 2) {
    int lm = 1 << (tb - 2);
    bool hc = (lane >> (cb - 2)) & 1;
#pragma unroll
    for (int k = 0; k < 4; ++k) {
      float o = __shfl_xor(v[k], lm);
      v[k] = hc ? o : v[k];
    }
  } else if (cb >= 2) {  // target in-register
    bool hc = (lane >> (cb - 2)) & 1;
    if (tb == 0) {
      float n0 = hc ? v[1] : v[0], n1 = hc ? v[0] : v[1];
      float n2 = hc ? v[3] : v[2], n3 = hc ? v[2] : v[3];
      v[0] = n0; v[1] = n1; v[2] = n2; v[3] = n3;
    } else {
      float n0 = hc ? v[2] : v[0], n2 = hc ? v[0] : v[2];
      float n1 = hc ? v[3] : v[1], n3 = hc ? v[1] : v[3];
      v[0] = n0; v[1] = n1; v[2] = n2; v[3] = n3;
    }
  } else if (tb >= 2) {  // control in-register, target cross-lane
    int lm = 1 << (tb - 2);
#pragma unroll
    for (int k = 0; k < 4; ++k) {
      float o = __shfl_xor(v[k], lm);
      if ((k >> cb) & 1) v[k] = o;
    }
  } else {               // both in-register
    if (cb == 0) { float t = v[1]; v[1] = v[3]; v[3] = t; }   // (cb,tb)=(0,1)
    else         { float t = v[2]; v[2] = v[3]; v[3] = t; }   // (cb,tb)=(1,0)
  }
}

// ---------------- stage-2 builder: full 16-dim state in registers ----------------
template <int BP>
__device__ __forceinline__ void ry16t(float* w, float c, float s) {
#pragma unroll
  for (int i = 0; i < 16; ++i) {
    if (((i >> BP) & 1) == 0) {
      const int j = i | (1 << BP);
      float a = w[i], b = w[j];
      w[i] = fmaf(s, b, c * a);
      w[j] = fmaf(-s, a, c * b);
    }
  }
}
__device__ __forceinline__ void ry16(float* w, int bp, float c, float s) {
  switch (bp) {
    case 0: ry16t<0>(w, c, s); break;
    case 1: ry16t<1>(w, c, s); break;
    case 2: ry16t<2>(w, c, s); break;
    default: ry16t<3>(w, c, s); break;
  }
}
template <int CB, int TB>
__device__ __forceinline__ void cnot16t(float* w) {
#pragma unroll
  for (int i = 0; i < 16; ++i) {
    if (((i >> CB) & 1) == 1 && ((i >> TB) & 1) == 0) {
      const int j = i | (1 << TB);
      float t = w[i]; w[i] = w[j]; w[j] = t;
    }
  }
}
__device__ __forceinline__ void cnot16(float* w, int cb, int tb) {
#define CC(a, b) if (cb == a && tb == b) { cnot16t<a, b>(w); return; }
  CC(0,1) CC(0,2) CC(0,3) CC(1,0) CC(1,2) CC(1,3)
  CC(2,0) CC(2,1) CC(2,3) CC(3,0) CC(3,1) CC(3,2)
#undef CC
}

__global__ void build_states_kernel(const float* __restrict__ thc,
                                    const float* __restrict__ th2,
                                    float* __restrict__ ws) {
  const int blk = blockIdx.x;
  const int lane = threadIdx.x;  // 64 threads
  if (blk < 16) {
    const float* th = thc + blk * 72;
    float v[4] = {0.f, 0.f, 0.f, 0.f};
    if (lane == 0) v[0] = 1.f;
    int p = 0;
    for (int m = 0; m < 8; ++m) {
#pragma unroll
      for (int q = 0; q < 8; ++q) {
        float a = 0.5f * th[p + q];
        ry8(v, lane, 7 - q, cosf(a), sinf(a));
      }
      p += 8;
#pragma unroll
      for (int q = 0; q < 8; ++q) {
        int tgt = (m % 2 == 0) ? ((q + 1) & 7) : ((q + 7) & 7);
        cnot8(v, lane, 7 - q, 7 - tgt);
      }
    }
#pragma unroll
    for (int q = 0; q < 8; ++q) {
      float a = 0.5f * th[p + q];
      ry8(v, lane, 7 - q, cosf(a), sinf(a));
    }
    float4* swv = (float4*)ws;
    swv[blk * 64 + lane] = make_float4(v[0], v[1], v[2], v[3]);
  } else {
    // U2[i][j] = ansatz(e_i)[j]; lane i (<16) builds row i entirely in registers
    float w[16];
#pragma unroll
    for (int j = 0; j < 16; ++j) w[j] = (j == lane) ? 1.f : 0.f;
    int p = 0;
    for (int m = 0; m < 8; ++m) {
#pragma unroll
      for (int q = 0; q < 4; ++q) {
        float a = 0.5f * th2[p + q];
        ry16(w, 3 - q, cosf(a), sinf(a));
      }
      p += 4;
#pragma unroll
      for (int q = 0; q < 4; ++q) {
        int tgt = (m % 2 == 0) ? ((q + 1) & 3) : ((q + 3) & 3);
        cnot16(w, 3 - q, 3 - tgt);
      }
    }
#pragma unroll
    for (int q = 0; q < 4; ++q) {
      float a = 0.5f * th2[p + q];
      ry16(w, 3 - q, cosf(a), sinf(a));
    }
    if (lane < 16) {
      float* u2 = ws + U2_OFF;
#pragma unroll
      for (int j = 0; j < 16; ++j) u2[lane * 16 + j] = w[j];
    }
  }
}

// ---------------- main kernel: ONE ROW PER LANE, zero shuffles ----------------
// Sw / U2 are read with wave-uniform indices -> compiler emits s_load and uses
// SGPR operands in v_fma (free operand fetch, no LDS, no shuffles).
__global__ __launch_bounds__(256, 2) void hadamard_main_kernel(
    const float* __restrict__ x, const float* __restrict__ ws,
    float* __restrict__ out) {
  const int row = blockIdx.x * 256 + threadIdx.x;
  const float* __restrict__ sw = ws;           // [16][256]
  const float* __restrict__ u2 = ws + U2_OFF;  // [16][16]

  const float4* __restrict__ xv = (const float4*)(x + (size_t)row * 256);

  float4 acc[16];
#pragma unroll
  for (int c = 0; c < 16; ++c) acc[c] = make_float4(0.f, 0.f, 0.f, 0.f);

  float4 xa[8], xb[8];
#pragma unroll
  for (int j = 0; j < 8; ++j) xa[j] = xv[j];

  // 8 sub-chunks of 32 floats; ping-pong double buffer; outer loop kept rolled
  // (4 iterations) so the body stays I$-resident.
#pragma unroll 1
  for (int sc = 0; sc < 8; sc += 2) {
    const int kbase = sc * 8;  // float4 index of xa's sub-chunk
    // prefetch sc+1
#pragma unroll
    for (int j = 0; j < 8; ++j) xb[j] = xv[kbase + 8 + j];
    // FMA over xa (sub-chunk sc): sw index is wave-uniform -> s_load
#pragma unroll
    for (int j = 0; j < 8; ++j) {
      const float* swk = sw + (kbase + j) * 4;
#pragma unroll
      for (int c = 0; c < 16; ++c) {
        const float s0 = swk[c * 256 + 0];
        const float s1 = swk[c * 256 + 1];
        const float s2 = swk[c * 256 + 2];
        const float s3 = swk[c * 256 + 3];
        acc[c].x = fmaf(xa[j].x, s0, acc[c].x);
        acc[c].y = fmaf(xa[j].y, s1, acc[c].y);
        acc[c].z = fmaf(xa[j].z, s2, acc[c].z);
        acc[c].w = fmaf(xa[j].w, s3, acc[c].w);
      }
    }
    // prefetch sc+2 into xa
    if (sc + 2 < 8) {
#pragma unroll
      for (int j = 0; j < 8; ++j) xa[j] = xv[kbase + 16 + j];
    }
    // FMA over xb (sub-chunk sc+1)
#pragma unroll
    for (int j = 0; j < 8; ++j) {
      const float* swk = sw + (kbase + 8 + j) * 4;
#pragma unroll
      for (int c = 0; c < 16; ++c) {
        const float s0 = swk[c * 256 + 0];
        const float s1 = swk[c * 256 + 1];
        const float s2 = swk[c * 256 + 2];
        const float s3 = swk[c * 256 + 3];
        acc[c].x = fmaf(xb[j].x, s0, acc[c].x);
        acc[c].y = fmaf(xb[j].y, s1, acc[c].y);
        acc[c].z = fmaf(xb[j].z, s2, acc[c].z);
        acc[c].w = fmaf(xb[j].w, s3, acc[c].w);
      }
    }
  }

  // ---------------- per-lane epilogue, no cross-lane ops ----------------
  float f[16];
  float ss = 0.f;
#pragma unroll
  for (int c = 0; c < 16; ++c) {
    float z = (acc[c].x + acc[c].y) + (acc[c].z + acc[c].w);
    float v = z / (1.f + __expf(-z));  // silu
    if (!isfinite(v)) v = 0.f;         // nan_to_num
    f[c] = v;
    ss = fmaf(v, v, ss);
  }
  const float fninv = 1.f / fmaxf(sqrtf(ss), 1e-6f);

  float S4[16];
#pragma unroll
  for (int j = 0; j < 16; ++j) S4[j] = 0.f;
#pragma unroll
  for (int c = 0; c < 16; ++c) {
    const float fc = f[c] * fninv;
#pragma unroll
    for (int j = 0; j < 16; ++j) S4[j] = fmaf(fc, u2[c * 16 + j], S4[j]);
  }

  float s4s = 0.f;
#pragma unroll
  for (int j = 0; j < 16; ++j) s4s = fmaf(S4[j], S4[j], s4s);
  const float inv = 1.f / fmaxf(sqrtf(s4s), 1e-6f);

  float P[8];
  float ps = 0.f;
#pragma unroll
  for (int t = 0; t < 8; ++t) {
    const float a = S4[t] * inv;
    const float b = S4[t + 8] * inv;
    float p = fmaf(a, a, b * b);
    p = fmaxf(p, 0.f);
    P[t] = p;
    ps += p;
  }
  const float rinv = 1.f / fmaxf(ps, 1e-6f);

  float lp[8];
#pragma unroll
  for (int t = 0; t < 8; ++t) {
    P[t] *= rinv;
    lp[t] = __logf(fmaxf(P[t], 1e-12f));
  }

  float4* o0 = (float4*)(out + (size_t)row * 8);
  o0[0] = make_float4(lp[0], lp[1], lp[2], lp[3]);
  o0[1] = make_float4(lp[4], lp[5], lp[6], lp[7]);
  float4* o1 = (float4*)(out + (size_t)N_ROWS * 8 + (size_t)row * 8);
  o1[0] = make_float4(P[0], P[1], P[2], P[3]);
  o1[1] = make_float4(P[4], P[5], P[6], P[7]);
}

extern "C" void kernel_launch(void* const* d_in, const int* in_sizes, int n_in,
                              void* d_out, int out_size, void* d_ws, size_t ws_size,
                              hipStream_t stream) {
  const float* x = (const float*)d_in[0];
  const float* thc = (const float*)d_in[1];
  const float* th2 = (const float*)d_in[2];
  float* out = (float*)d_out;
  float* ws = (float*)d_ws;

  build_states_kernel<<<17, 64, 0, stream>>>(thc, th2, ws);
  hadamard_main_kernel<<<N_ROWS / 256, 256, 0, stream>>>(x, ws, out);
}